// Round 1
// baseline (420.045 us; speedup 1.0000x reference)
//
#include <hip/hip_runtime.h>

#define NPOS 384
#define DMODEL 512
#define NH 8
#define DK 64
#define BS 8

// ---------------- generic NN GEMM: C = (A @ B + bias) * scale ----------------
// tile 64x64, BK=16, 256 threads, 4x4 micro-tile
__global__ __launch_bounds__(256) void gemm_nn_bias(
    const float* __restrict__ A, int lda,
    const float* __restrict__ B, int ldb,
    float* __restrict__ C, int ldc, int K,
    const float* __restrict__ bias, float outscale) {
  __shared__ float As[16][64];  // [k][m]
  __shared__ float Bs[16][64];  // [k][n]
  const int tid = threadIdx.x;
  const int tx = tid & 15, ty = tid >> 4;
  const int m0 = blockIdx.x * 64, n0 = blockIdx.y * 64;
  const int ma = tid >> 2, ka = (tid & 3) * 4;
  const int kb = tid >> 4, nb = (tid & 15) * 4;
  float acc[4][4] = {};
  for (int k0 = 0; k0 < K; k0 += 16) {
    float4 a = *(const float4*)&A[(size_t)(m0 + ma) * lda + k0 + ka];
    As[ka + 0][ma] = a.x; As[ka + 1][ma] = a.y;
    As[ka + 2][ma] = a.z; As[ka + 3][ma] = a.w;
    *(float4*)&Bs[kb][nb] = *(const float4*)&B[(size_t)(k0 + kb) * ldb + n0 + nb];
    __syncthreads();
#pragma unroll
    for (int kk = 0; kk < 16; ++kk) {
      float4 av = *(const float4*)&As[kk][ty * 4];
      float4 bv = *(const float4*)&Bs[kk][tx * 4];
      float a_[4] = {av.x, av.y, av.z, av.w};
      float b_[4] = {bv.x, bv.y, bv.z, bv.w};
#pragma unroll
      for (int i = 0; i < 4; ++i)
#pragma unroll
        for (int j = 0; j < 4; ++j) acc[i][j] += a_[i] * b_[j];
    }
    __syncthreads();
  }
  float4 bi = make_float4(0.f, 0.f, 0.f, 0.f);
  if (bias) bi = *(const float4*)&bias[n0 + tx * 4];
#pragma unroll
  for (int i = 0; i < 4; ++i) {
    float4 o;
    o.x = (acc[i][0] + bi.x) * outscale;
    o.y = (acc[i][1] + bi.y) * outscale;
    o.z = (acc[i][2] + bi.z) * outscale;
    o.w = (acc[i][3] + bi.w) * outscale;
    *(float4*)&C[(size_t)(m0 + ty * 4 + i) * ldc + n0 + tx * 4] = o;
  }
}

// ---------------- pos scores: scores[b,h,n,m] = qh_scaled[b,n,h,:].rk[n,m,h,:]
// grid (12 n-tiles, 12 m-tiles, 8 h). Pure write of scores (runs first).
// b is the fastest lane dim so 8 lanes broadcast-share each rk float4 read;
// rpos_k is streamed from HBM exactly once in total.
__global__ __launch_bounds__(256) void pos_scores_kernel(
    const float* __restrict__ qh,   // (b, n, h*64+d), pre-scaled by 1/8
    const float* __restrict__ rk,   // (n, m, h, d)
    float* __restrict__ scores) {   // (b, h, n, m)
  const int h = blockIdx.z;
  const int n0 = blockIdx.x * 32;
  const int m0 = blockIdx.y * 32;
  const int tid = threadIdx.x;
  const int b = tid & 7;
#pragma unroll 1
  for (int r = 0; r < 4; ++r) {
    const int p = r * 32 + (tid >> 3);   // 0..127
    const int n = n0 + (p >> 2);
    const int mg = (p & 3) * 8;
    const float* qrow = qh + ((size_t)b * NPOS + n) * DMODEL + h * DK;
    const float* rkb = rk + ((size_t)(n * NPOS + m0 + mg) * NH + h) * DK;
    float4 qreg[16];
#pragma unroll
    for (int d4 = 0; d4 < 16; ++d4) qreg[d4] = *(const float4*)&qrow[d4 * 4];
    float acc[8];
#pragma unroll
    for (int mm = 0; mm < 8; ++mm) {
      const float4* rv = (const float4*)&rkb[(size_t)mm * NH * DK];
      float s = 0.f;
#pragma unroll
      for (int d4 = 0; d4 < 16; ++d4) {
        float4 v = rv[d4];
        s += qreg[d4].x * v.x + qreg[d4].y * v.y + qreg[d4].z * v.z + qreg[d4].w * v.w;
      }
      acc[mm] = s;
    }
    float* srow = scores + (((size_t)(b * NH + h) * NPOS + n)) * NPOS + m0 + mg;
    float4 o0 = make_float4(acc[0], acc[1], acc[2], acc[3]);
    float4 o1 = make_float4(acc[4], acc[5], acc[6], acc[7]);
    *(float4*)&srow[0] = o0;
    *(float4*)&srow[4] = o1;
  }
}

// ---------------- std scores (NT, K=64, single LDS stage), adds into scores
// grid (6 n-tiles, 6 m-tiles, 64 z=b*8+h)
__global__ __launch_bounds__(256) void gemm_nt_addinto(
    const float* __restrict__ qh, const float* __restrict__ kh,
    float* __restrict__ scores) {
  const int z = blockIdx.z, b = z >> 3, h = z & 7;
  const float* A = qh + (size_t)b * NPOS * DMODEL + h * DK;   // lda DMODEL
  const float* Bt = kh + (size_t)b * NPOS * DMODEL + h * DK;  // ldb DMODEL
  float* C = scores + (size_t)z * NPOS * NPOS;                // ldc NPOS
  __shared__ float As[64][68];  // [d][n]
  __shared__ float Bs[64][68];  // [d][m]
  const int tid = threadIdx.x;
  const int tx = tid & 15, ty = tid >> 4;
  const int n0 = blockIdx.x * 64, m0 = blockIdx.y * 64;
  {
    const int rrow = tid >> 2;
#pragma unroll
    for (int it = 0; it < 4; ++it) {
      const int d4 = (tid & 3) + it * 4;
      float4 a = *(const float4*)&A[(size_t)(n0 + rrow) * DMODEL + d4 * 4];
      As[d4 * 4 + 0][rrow] = a.x; As[d4 * 4 + 1][rrow] = a.y;
      As[d4 * 4 + 2][rrow] = a.z; As[d4 * 4 + 3][rrow] = a.w;
      float4 bb = *(const float4*)&Bt[(size_t)(m0 + rrow) * DMODEL + d4 * 4];
      Bs[d4 * 4 + 0][rrow] = bb.x; Bs[d4 * 4 + 1][rrow] = bb.y;
      Bs[d4 * 4 + 2][rrow] = bb.z; Bs[d4 * 4 + 3][rrow] = bb.w;
    }
  }
  __syncthreads();
  float acc[4][4] = {};
#pragma unroll
  for (int d = 0; d < 64; ++d) {
    float4 av = *(const float4*)&As[d][ty * 4];
    float4 bv = *(const float4*)&Bs[d][tx * 4];
    float a_[4] = {av.x, av.y, av.z, av.w};
    float b_[4] = {bv.x, bv.y, bv.z, bv.w};
#pragma unroll
    for (int i = 0; i < 4; ++i)
#pragma unroll
      for (int j = 0; j < 4; ++j) acc[i][j] += a_[i] * b_[j];
  }
#pragma unroll
  for (int i = 0; i < 4; ++i) {
    float* crow = &C[(size_t)(n0 + ty * 4 + i) * NPOS + m0 + tx * 4];
    float4 c = *(float4*)crow;
    c.x += acc[i][0]; c.y += acc[i][1];
    c.z += acc[i][2]; c.w += acc[i][3];
    *(float4*)crow = c;
  }
}

// ---------------- row softmax over m, in place; folds the second 1/sqrt(dk)
// one wave per row; block = 4 waves; grid = 24576/4
__global__ __launch_bounds__(256) void softmax_kernel(float* __restrict__ scores) {
  const int row = blockIdx.x * 4 + (threadIdx.x >> 6);
  const int lane = threadIdx.x & 63;
  float* s = scores + (size_t)row * NPOS;
  float v[6];
  float mx = -1e30f;
#pragma unroll
  for (int j = 0; j < 6; ++j) {
    v[j] = s[j * 64 + lane];
    mx = fmaxf(mx, v[j]);
  }
#pragma unroll
  for (int o = 32; o; o >>= 1) mx = fmaxf(mx, __shfl_xor(mx, o, 64));
  float sum = 0.f;
#pragma unroll
  for (int j = 0; j < 6; ++j) {
    v[j] = __expf(v[j] - mx);
    sum += v[j];
  }
#pragma unroll
  for (int o = 32; o; o >>= 1) sum += __shfl_xor(sum, o, 64);
  const float inv = 0.125f / sum;
#pragma unroll
  for (int j = 0; j < 6; ++j) s[j * 64 + lane] = v[j] * inv;
}

// ---------------- PV: attn[b,n,h*64+d] = sum_m P[b,h,n,m] * V[b,m,h*64+d]
// grid (6 n-tiles, 1, 64 z)
__global__ __launch_bounds__(256) void gemm_pv(
    const float* __restrict__ P, const float* __restrict__ Vsrc,
    float* __restrict__ attn) {
  const int z = blockIdx.z, b = z >> 3, h = z & 7;
  const float* A = P + (size_t)z * NPOS * NPOS;                   // lda NPOS
  const float* B = Vsrc + (size_t)b * NPOS * DMODEL + h * DK;     // ldb DMODEL
  float* C = attn + (size_t)b * NPOS * DMODEL + h * DK;           // ldc DMODEL
  __shared__ float As[16][64];
  __shared__ float Bs[16][64];
  const int tid = threadIdx.x;
  const int tx = tid & 15, ty = tid >> 4;
  const int m0 = blockIdx.x * 64;
  const int ma = tid >> 2, ka = (tid & 3) * 4;
  const int kb = tid >> 4, nb = (tid & 15) * 4;
  float acc[4][4] = {};
  for (int k0 = 0; k0 < NPOS; k0 += 16) {
    float4 a = *(const float4*)&A[(size_t)(m0 + ma) * NPOS + k0 + ka];
    As[ka + 0][ma] = a.x; As[ka + 1][ma] = a.y;
    As[ka + 2][ma] = a.z; As[ka + 3][ma] = a.w;
    *(float4*)&Bs[kb][nb] = *(const float4*)&B[(size_t)(k0 + kb) * DMODEL + nb];
    __syncthreads();
#pragma unroll
    for (int kk = 0; kk < 16; ++kk) {
      float4 av = *(const float4*)&As[kk][ty * 4];
      float4 bv = *(const float4*)&Bs[kk][tx * 4];
      float a_[4] = {av.x, av.y, av.z, av.w};
      float b_[4] = {bv.x, bv.y, bv.z, bv.w};
#pragma unroll
      for (int i = 0; i < 4; ++i)
#pragma unroll
        for (int j = 0; j < 4; ++j) acc[i][j] += a_[i] * b_[j];
    }
    __syncthreads();
  }
#pragma unroll
  for (int i = 0; i < 4; ++i) {
    float4 o = make_float4(acc[i][0], acc[i][1], acc[i][2], acc[i][3]);
    *(float4*)&C[(size_t)(m0 + ty * 4 + i) * DMODEL + tx * 4] = o;
  }
}

extern "C" void kernel_launch(void* const* d_in, const int* in_sizes, int n_in,
                              void* d_out, int out_size, void* d_ws, size_t ws_size,
                              hipStream_t stream) {
  const float* q  = (const float*)d_in[0];
  const float* k  = (const float*)d_in[1];
  const float* v  = (const float*)d_in[2];
  const float* rk = (const float*)d_in[3];
  // d_in[4] = rpos_v: unused by the reference
  const float* Wq = (const float*)d_in[5];
  const float* bq = (const float*)d_in[6];
  const float* Wk = (const float*)d_in[7];
  const float* bk = (const float*)d_in[8];
  const float* Wv = (const float*)d_in[9];
  const float* bv = (const float*)d_in[10];
  const float* Wo = (const float*)d_in[11];
  const float* bo = (const float*)d_in[12];

  const size_t TOK = (size_t)BS * NPOS * DMODEL;  // 1,572,864
  float* qh = (float*)d_ws;
  float* kh = qh + TOK;
  float* scores = kh + TOK;                       // 8*8*384*384 = 9,437,184
  float* attn = scores + (size_t)BS * NH * NPOS * NPOS;
  float* origv = (float*)d_out;
  float* outp = origv + TOK;

  dim3 blk(256);

  // projections (M=3072, N=512, K=512). qh is pre-scaled by 1/sqrt(dk)=0.125.
  gemm_nn_bias<<<dim3(48, 8), blk, 0, stream>>>(q, DMODEL, Wq, DMODEL, qh, DMODEL,
                                                DMODEL, bq, 0.125f);
  gemm_nn_bias<<<dim3(48, 8), blk, 0, stream>>>(k, DMODEL, Wk, DMODEL, kh, DMODEL,
                                                DMODEL, bk, 1.0f);
  gemm_nn_bias<<<dim3(48, 8), blk, 0, stream>>>(v, DMODEL, Wv, DMODEL, origv, DMODEL,
                                                DMODEL, bv, 1.0f);

  // pos scores (writes scores), then std scores (adds into scores)
  pos_scores_kernel<<<dim3(12, 12, 8), blk, 0, stream>>>(qh, rk, scores);
  gemm_nt_addinto<<<dim3(6, 6, 64), blk, 0, stream>>>(qh, kh, scores);

  // softmax rows (folds second 1/sqrt(dk))
  softmax_kernel<<<dim3((BS * NH * NPOS) / 4), blk, 0, stream>>>(scores);

  // PV
  gemm_pv<<<dim3(6, 1, 64), blk, 0, stream>>>(scores, origv, attn);

  // output projection
  gemm_nn_bias<<<dim3(48, 8), blk, 0, stream>>>(attn, DMODEL, Wo, DMODEL, outp, DMODEL,
                                                DMODEL, bo, 1.0f);
}

// Round 2
// 336.610 us; speedup vs baseline: 1.2479x; 1.2479x over previous
//
#include <hip/hip_runtime.h>

#define NPOS 384
#define DMODEL 512
#define NH 8
#define DK 64
#define BS 8

// ---------------- generic NN GEMM: C = (A @ B + bias) * scale ----------------
// tile 64x64, BK=16, 256 threads, 4x4 micro-tile
__global__ __launch_bounds__(256) void gemm_nn_bias(
    const float* __restrict__ A, int lda,
    const float* __restrict__ B, int ldb,
    float* __restrict__ C, int ldc, int K,
    const float* __restrict__ bias, float outscale) {
  __shared__ float As[16][64];  // [k][m]
  __shared__ float Bs[16][64];  // [k][n]
  const int tid = threadIdx.x;
  const int tx = tid & 15, ty = tid >> 4;
  const int m0 = blockIdx.x * 64, n0 = blockIdx.y * 64;
  const int ma = tid >> 2, ka = (tid & 3) * 4;
  const int kb = tid >> 4, nb = (tid & 15) * 4;
  float acc[4][4] = {};
  for (int k0 = 0; k0 < K; k0 += 16) {
    float4 a = *(const float4*)&A[(size_t)(m0 + ma) * lda + k0 + ka];
    As[ka + 0][ma] = a.x; As[ka + 1][ma] = a.y;
    As[ka + 2][ma] = a.z; As[ka + 3][ma] = a.w;
    *(float4*)&Bs[kb][nb] = *(const float4*)&B[(size_t)(k0 + kb) * ldb + n0 + nb];
    __syncthreads();
#pragma unroll
    for (int kk = 0; kk < 16; ++kk) {
      float4 av = *(const float4*)&As[kk][ty * 4];
      float4 bv = *(const float4*)&Bs[kk][tx * 4];
      float a_[4] = {av.x, av.y, av.z, av.w};
      float b_[4] = {bv.x, bv.y, bv.z, bv.w};
#pragma unroll
      for (int i = 0; i < 4; ++i)
#pragma unroll
        for (int j = 0; j < 4; ++j) acc[i][j] += a_[i] * b_[j];
    }
    __syncthreads();
  }
  float4 bi = make_float4(0.f, 0.f, 0.f, 0.f);
  if (bias) bi = *(const float4*)&bias[n0 + tx * 4];
#pragma unroll
  for (int i = 0; i < 4; ++i) {
    float4 o;
    o.x = (acc[i][0] + bi.x) * outscale;
    o.y = (acc[i][1] + bi.y) * outscale;
    o.z = (acc[i][2] + bi.z) * outscale;
    o.w = (acc[i][3] + bi.w) * outscale;
    *(float4*)&C[(size_t)(m0 + ty * 4 + i) * ldc + n0 + tx * 4] = o;
  }
}

// ---------------- std scores (NT, K=64, single LDS stage), WRITES scores
// grid (6 n-tiles, 6 m-tiles, 64 z=b*8+h)
__global__ __launch_bounds__(256) void gemm_nt_store(
    const float* __restrict__ qh, const float* __restrict__ kh,
    float* __restrict__ scores) {
  const int z = blockIdx.z, b = z >> 3, h = z & 7;
  const float* A = qh + (size_t)b * NPOS * DMODEL + h * DK;   // lda DMODEL
  const float* Bt = kh + (size_t)b * NPOS * DMODEL + h * DK;  // ldb DMODEL
  float* C = scores + (size_t)z * NPOS * NPOS;                // ldc NPOS
  __shared__ float As[64][68];  // [d][n]
  __shared__ float Bs[64][68];  // [d][m]
  const int tid = threadIdx.x;
  const int tx = tid & 15, ty = tid >> 4;
  const int n0 = blockIdx.x * 64, m0 = blockIdx.y * 64;
  {
    const int rrow = tid >> 2;
#pragma unroll
    for (int it = 0; it < 4; ++it) {
      const int d4 = (tid & 3) + it * 4;
      float4 a = *(const float4*)&A[(size_t)(n0 + rrow) * DMODEL + d4 * 4];
      As[d4 * 4 + 0][rrow] = a.x; As[d4 * 4 + 1][rrow] = a.y;
      As[d4 * 4 + 2][rrow] = a.z; As[d4 * 4 + 3][rrow] = a.w;
      float4 bb = *(const float4*)&Bt[(size_t)(m0 + rrow) * DMODEL + d4 * 4];
      Bs[d4 * 4 + 0][rrow] = bb.x; Bs[d4 * 4 + 1][rrow] = bb.y;
      Bs[d4 * 4 + 2][rrow] = bb.z; Bs[d4 * 4 + 3][rrow] = bb.w;
    }
  }
  __syncthreads();
  float acc[4][4] = {};
#pragma unroll
  for (int d = 0; d < 64; ++d) {
    float4 av = *(const float4*)&As[d][ty * 4];
    float4 bv = *(const float4*)&Bs[d][tx * 4];
    float a_[4] = {av.x, av.y, av.z, av.w};
    float b_[4] = {bv.x, bv.y, bv.z, bv.w};
#pragma unroll
    for (int i = 0; i < 4; ++i)
#pragma unroll
      for (int j = 0; j < 4; ++j) acc[i][j] += a_[i] * b_[j];
  }
#pragma unroll
  for (int i = 0; i < 4; ++i) {
    float* crow = &C[(size_t)(n0 + ty * 4 + i) * NPOS + m0 + tx * 4];
    *(float4*)crow = make_float4(acc[i][0], acc[i][1], acc[i][2], acc[i][3]);
  }
}

// ---------------- pos scores v2: scores[b,h,n,m] += qh_scaled[b,n,h,:].rk[n,m,h,:]
// One block per (n, 16-m tile). rk chunk (16x512 fp32 = 32 KB) staged into LDS
// with fully-coalesced float4 loads; padded rows [16][8][68] make the 8
// h-addresses of each compute ds_read_b128 hit disjoint bank quads.
// grid (24 m-tiles, 384 n). 9216 blocks -> 36 blocks/CU queued for latency hiding.
__global__ __launch_bounds__(256) void pos_scores_v2(
    const float* __restrict__ qh,   // (b, n, 512), pre-scaled by 1/8
    const float* __restrict__ rk,   // (n, m, h, d)
    float* __restrict__ scores) {   // (b, h, n, m) -- ADD into
  __shared__ float rks[16][8][68];  // 34816 B
  const int n = blockIdx.y;
  const int m0 = blockIdx.x * 16;
  const int t = threadIdx.x;

  // q row for this thread's (b,h): 16 float4 in registers (L2-resident source)
  const int b = t & 7, h = (t >> 3) & 7, mg = t >> 6;
  const float* qrow = qh + ((size_t)b * NPOS + n) * DMODEL + h * DK;
  float4 qreg[16];
#pragma unroll
  for (int d4 = 0; d4 < 16; ++d4) qreg[d4] = ((const float4*)qrow)[d4];

  // stage rk[n, m0..m0+15, :, :] coalesced -> padded LDS
  const float4* src = (const float4*)(rk + ((size_t)n * NPOS + m0) * (NH * DK));
#pragma unroll
  for (int kI = 0; kI < 8; ++kI) {
    const int f = t + kI * 256;       // float4 index 0..2047
    const float4 val = src[f];
    const int m = f >> 7, hh = (f >> 4) & 7, d4 = f & 15;
    *(float4*)&rks[m][hh][d4 * 4] = val;
  }
  __syncthreads();

  // compute 4 outputs: m = mg*4 + j
  const int mb = mg * 4;
  float4 a0 = make_float4(0.f, 0.f, 0.f, 0.f);
  float4 a1 = a0, a2 = a0, a3 = a0;
#pragma unroll
  for (int d4 = 0; d4 < 16; ++d4) {
    const float4 qv = qreg[d4];
    const float4 r0 = *(const float4*)&rks[mb + 0][h][d4 * 4];
    const float4 r1 = *(const float4*)&rks[mb + 1][h][d4 * 4];
    const float4 r2 = *(const float4*)&rks[mb + 2][h][d4 * 4];
    const float4 r3 = *(const float4*)&rks[mb + 3][h][d4 * 4];
    a0.x += qv.x * r0.x; a0.y += qv.y * r0.y; a0.z += qv.z * r0.z; a0.w += qv.w * r0.w;
    a1.x += qv.x * r1.x; a1.y += qv.y * r1.y; a1.z += qv.z * r1.z; a1.w += qv.w * r1.w;
    a2.x += qv.x * r2.x; a2.y += qv.y * r2.y; a2.z += qv.z * r2.z; a2.w += qv.w * r2.w;
    a3.x += qv.x * r3.x; a3.y += qv.y * r3.y; a3.z += qv.z * r3.z; a3.w += qv.w * r3.w;
  }
  float* srow = scores + ((size_t)(b * NH + h) * NPOS + n) * NPOS + m0 + mb;
  float4 c = *(float4*)srow;
  c.x += a0.x + a0.y + a0.z + a0.w;
  c.y += a1.x + a1.y + a1.z + a1.w;
  c.z += a2.x + a2.y + a2.z + a2.w;
  c.w += a3.x + a3.y + a3.z + a3.w;
  *(float4*)srow = c;
}

// ---------------- row softmax over m, in place; folds the second 1/sqrt(dk)
__global__ __launch_bounds__(256) void softmax_kernel(float* __restrict__ scores) {
  const int row = blockIdx.x * 4 + (threadIdx.x >> 6);
  const int lane = threadIdx.x & 63;
  float* s = scores + (size_t)row * NPOS;
  float v[6];
  float mx = -1e30f;
#pragma unroll
  for (int j = 0; j < 6; ++j) {
    v[j] = s[j * 64 + lane];
    mx = fmaxf(mx, v[j]);
  }
#pragma unroll
  for (int o = 32; o; o >>= 1) mx = fmaxf(mx, __shfl_xor(mx, o, 64));
  float sum = 0.f;
#pragma unroll
  for (int j = 0; j < 6; ++j) {
    v[j] = __expf(v[j] - mx);
    sum += v[j];
  }
#pragma unroll
  for (int o = 32; o; o >>= 1) sum += __shfl_xor(sum, o, 64);
  const float inv = 0.125f / sum;
#pragma unroll
  for (int j = 0; j < 6; ++j) s[j * 64 + lane] = v[j] * inv;
}

// ---------------- PV: attn[b,n,h*64+d] = sum_m P[b,h,n,m] * V[b,m,h*64+d]
__global__ __launch_bounds__(256) void gemm_pv(
    const float* __restrict__ P, const float* __restrict__ Vsrc,
    float* __restrict__ attn) {
  const int z = blockIdx.z, b = z >> 3, h = z & 7;
  const float* A = P + (size_t)z * NPOS * NPOS;                   // lda NPOS
  const float* B = Vsrc + (size_t)b * NPOS * DMODEL + h * DK;     // ldb DMODEL
  float* C = attn + (size_t)b * NPOS * DMODEL + h * DK;           // ldc DMODEL
  __shared__ float As[16][64];
  __shared__ float Bs[16][64];
  const int tid = threadIdx.x;
  const int tx = tid & 15, ty = tid >> 4;
  const int m0 = blockIdx.x * 64;
  const int ma = tid >> 2, ka = (tid & 3) * 4;
  const int kb = tid >> 4, nb = (tid & 15) * 4;
  float acc[4][4] = {};
  for (int k0 = 0; k0 < NPOS; k0 += 16) {
    float4 a = *(const float4*)&A[(size_t)(m0 + ma) * NPOS + k0 + ka];
    As[ka + 0][ma] = a.x; As[ka + 1][ma] = a.y;
    As[ka + 2][ma] = a.z; As[ka + 3][ma] = a.w;
    *(float4*)&Bs[kb][nb] = *(const float4*)&B[(size_t)(k0 + kb) * DMODEL + nb];
    __syncthreads();
#pragma unroll
    for (int kk = 0; kk < 16; ++kk) {
      float4 av = *(const float4*)&As[kk][ty * 4];
      float4 bv = *(const float4*)&Bs[kk][tx * 4];
      float a_[4] = {av.x, av.y, av.z, av.w};
      float b_[4] = {bv.x, bv.y, bv.z, bv.w};
#pragma unroll
      for (int i = 0; i < 4; ++i)
#pragma unroll
        for (int j = 0; j < 4; ++j) acc[i][j] += a_[i] * b_[j];
    }
    __syncthreads();
  }
#pragma unroll
  for (int i = 0; i < 4; ++i) {
    float4 o = make_float4(acc[i][0], acc[i][1], acc[i][2], acc[i][3]);
    *(float4*)&C[(size_t)(m0 + ty * 4 + i) * DMODEL + tx * 4] = o;
  }
}

extern "C" void kernel_launch(void* const* d_in, const int* in_sizes, int n_in,
                              void* d_out, int out_size, void* d_ws, size_t ws_size,
                              hipStream_t stream) {
  const float* q  = (const float*)d_in[0];
  const float* k  = (const float*)d_in[1];
  const float* v  = (const float*)d_in[2];
  const float* rk = (const float*)d_in[3];
  // d_in[4] = rpos_v: unused by the reference
  const float* Wq = (const float*)d_in[5];
  const float* bq = (const float*)d_in[6];
  const float* Wk = (const float*)d_in[7];
  const float* bk = (const float*)d_in[8];
  const float* Wv = (const float*)d_in[9];
  const float* bv = (const float*)d_in[10];
  const float* Wo = (const float*)d_in[11];
  const float* bo = (const float*)d_in[12];

  const size_t TOK = (size_t)BS * NPOS * DMODEL;  // 1,572,864
  float* qh = (float*)d_ws;
  float* kh = qh + TOK;
  float* scores = kh + TOK;                       // 8*8*384*384 = 9,437,184
  float* attn = scores + (size_t)BS * NH * NPOS * NPOS;
  float* origv = (float*)d_out;
  float* outp = origv + TOK;

  dim3 blk(256);

  // projections (M=3072, N=512, K=512). qh is pre-scaled by 1/sqrt(dk)=0.125.
  gemm_nn_bias<<<dim3(48, 8), blk, 0, stream>>>(q, DMODEL, Wq, DMODEL, qh, DMODEL,
                                                DMODEL, bq, 0.125f);
  gemm_nn_bias<<<dim3(48, 8), blk, 0, stream>>>(k, DMODEL, Wk, DMODEL, kh, DMODEL,
                                                DMODEL, bk, 1.0f);
  gemm_nn_bias<<<dim3(48, 8), blk, 0, stream>>>(v, DMODEL, Wv, DMODEL, origv, DMODEL,
                                                DMODEL, bv, 1.0f);

  // std scores write scores, then pos scores add into them
  gemm_nt_store<<<dim3(6, 6, 64), blk, 0, stream>>>(qh, kh, scores);
  pos_scores_v2<<<dim3(24, 384), blk, 0, stream>>>(qh, rk, scores);

  // softmax rows (folds second 1/sqrt(dk))
  softmax_kernel<<<dim3((BS * NH * NPOS) / 4), blk, 0, stream>>>(scores);

  // PV
  gemm_pv<<<dim3(6, 1, 64), blk, 0, stream>>>(scores, origv, attn);

  // output projection
  gemm_nn_bias<<<dim3(48, 8), blk, 0, stream>>>(attn, DMODEL, Wo, DMODEL, outp, DMODEL,
                                                DMODEL, bo, 1.0f);
}

// Round 3
// 175.844 us; speedup vs baseline: 2.3887x; 1.9142x over previous
//
#include <hip/hip_runtime.h>

#define NPOS 384
#define DMODEL 512
#define NH 8
#define DK 64
#define BS 8
#define MROWS (BS * NPOS)     // 3072
#define SROW (NPOS * NPOS)    // 147456

typedef __attribute__((ext_vector_type(8))) short bf16x8;
typedef __attribute__((ext_vector_type(4))) float f32x4;

__device__ __forceinline__ unsigned short f2bf(float x) {
  unsigned int u = __float_as_uint(x);
  return (unsigned short)((u + 0x7fffu + ((u >> 16) & 1u)) >> 16);
}
__device__ __forceinline__ float bflo(unsigned int v) { return __uint_as_float(v << 16); }
__device__ __forceinline__ float bfhi(unsigned int v) { return __uint_as_float(v & 0xffff0000u); }

// ---------- K1: transpose-convert the 4 weight matrices to bf16 [n][k] ----------
__global__ __launch_bounds__(256) void convert_w(
    const float* __restrict__ Wq, const float* __restrict__ Wk,
    const float* __restrict__ Wv, const float* __restrict__ Wo,
    unsigned short* __restrict__ wt) {
  __shared__ float s[64][68];
  const int z = blockIdx.z;
  const float* W = z == 0 ? Wq : z == 1 ? Wk : z == 2 ? Wv : Wo;
  unsigned short* out = wt + (size_t)z * DMODEL * DMODEL;
  const int k0 = blockIdx.x * 64, n0 = blockIdx.y * 64;
  const int t = threadIdx.x;
#pragma unroll
  for (int i = 0; i < 4; ++i) {
    int f = t + i * 256;
    int kr = f >> 4, q4 = f & 15;
    *(float4*)&s[kr][q4 * 4] = *(const float4*)&W[(size_t)(k0 + kr) * DMODEL + n0 + q4 * 4];
  }
  __syncthreads();
#pragma unroll
  for (int i = 0; i < 2; ++i) {
    int slot = t + i * 256;
    int n = slot >> 3, kq = slot & 7;
    unsigned int p[4];
#pragma unroll
    for (int j = 0; j < 4; ++j) {
      unsigned short l0 = f2bf(s[kq * 8 + j * 2][n]);
      unsigned short h0 = f2bf(s[kq * 8 + j * 2 + 1][n]);
      p[j] = (unsigned)l0 | ((unsigned)h0 << 16);
    }
    *(uint4*)&out[(size_t)(n0 + n) * DMODEL + k0 + kq * 8] = make_uint4(p[0], p[1], p[2], p[3]);
  }
}

// ---------- K2: fused Q/K/V projections via MFMA (z selects) ----------
// tile 64x64, BK=64, 4 waves (2x2), wave computes 32x32.
__global__ __launch_bounds__(256) void proj_qkv(
    const float* __restrict__ qin, const float* __restrict__ kin, const float* __restrict__ vin,
    const unsigned short* __restrict__ wt,
    const float* __restrict__ bq, const float* __restrict__ bk, const float* __restrict__ bv,
    unsigned short* __restrict__ qhb, unsigned short* __restrict__ khb,
    float* __restrict__ origv, unsigned short* __restrict__ vhT) {
  __shared__ unsigned short As[64][72];
  __shared__ unsigned short Bs[64][72];
  const int z = blockIdx.z;
  const float* A = z == 0 ? qin : z == 1 ? kin : vin;
  const unsigned short* Wt = wt + (size_t)z * DMODEL * DMODEL;
  const float* bias = z == 0 ? bq : z == 1 ? bk : bv;
  const int m0 = blockIdx.x * 64, n0 = blockIdx.y * 64;
  const int t = threadIdx.x, lane = t & 63, w = t >> 6;
  const int wr = w >> 1, wc = w & 1;
  const int l15 = lane & 15, l4 = lane >> 4;
  f32x4 acc[2][2] = {};
  for (int kt = 0; kt < 8; ++kt) {
    const int k0 = kt * 64;
#pragma unroll
    for (int i = 0; i < 4; ++i) {
      int f = t + i * 256;
      int row = f >> 4, q4 = f & 15;
      float4 a = *(const float4*)&A[(size_t)(m0 + row) * DMODEL + k0 + q4 * 4];
      unsigned int p0 = (unsigned)f2bf(a.x) | ((unsigned)f2bf(a.y) << 16);
      unsigned int p1 = (unsigned)f2bf(a.z) | ((unsigned)f2bf(a.w) << 16);
      *(uint2*)&As[row][q4 * 4] = make_uint2(p0, p1);
    }
#pragma unroll
    for (int i = 0; i < 2; ++i) {
      int s = t + i * 256;
      int row = s >> 3, kq = s & 7;
      *(uint4*)&Bs[row][kq * 8] = *(const uint4*)&Wt[(size_t)(n0 + row) * DMODEL + k0 + kq * 8];
    }
    __syncthreads();
    bf16x8 af[2][2], bfr[2][2];
#pragma unroll
    for (int mf = 0; mf < 2; ++mf)
#pragma unroll
      for (int ks = 0; ks < 2; ++ks)
        af[mf][ks] = *(const bf16x8*)&As[wr * 32 + mf * 16 + l15][ks * 32 + l4 * 8];
#pragma unroll
    for (int nf = 0; nf < 2; ++nf)
#pragma unroll
      for (int ks = 0; ks < 2; ++ks)
        bfr[nf][ks] = *(const bf16x8*)&Bs[wc * 32 + nf * 16 + l15][ks * 32 + l4 * 8];
#pragma unroll
    for (int mf = 0; mf < 2; ++mf)
#pragma unroll
      for (int nf = 0; nf < 2; ++nf)
#pragma unroll
        for (int ks = 0; ks < 2; ++ks)
          acc[mf][nf] = __builtin_amdgcn_mfma_f32_16x16x32_bf16(af[mf][ks], bfr[nf][ks],
                                                                acc[mf][nf], 0, 0, 0);
    __syncthreads();
  }
#pragma unroll
  for (int mf = 0; mf < 2; ++mf)
#pragma unroll
    for (int nf = 0; nf < 2; ++nf) {
      const int row0 = m0 + wr * 32 + mf * 16 + l4 * 4;
      const int col = n0 + wc * 32 + nf * 16 + l15;
      const float bi = bias[col];
      if (z == 0) {
#pragma unroll
        for (int i = 0; i < 4; ++i)
          qhb[(size_t)(row0 + i) * DMODEL + col] = f2bf((acc[mf][nf][i] + bi) * 0.125f);
      } else if (z == 1) {
#pragma unroll
        for (int i = 0; i < 4; ++i)
          khb[(size_t)(row0 + i) * DMODEL + col] = f2bf(acc[mf][nf][i] + bi);
      } else {
        const int b = row0 / NPOS, n = row0 - b * NPOS;
        const int h = col >> 6, d = col & 63;
        float vals[4];
#pragma unroll
        for (int i = 0; i < 4; ++i) {
          vals[i] = acc[mf][nf][i] + bi;
          origv[(size_t)(row0 + i) * DMODEL + col] = vals[i];
        }
        ushort4 pk;
        pk.x = f2bf(vals[0]); pk.y = f2bf(vals[1]);
        pk.z = f2bf(vals[2]); pk.w = f2bf(vals[3]);
        *(ushort4*)&vhT[((size_t)((b * NH + h) * DK + d)) * NPOS + n] = pk;
      }
    }
}

// ---------- K3: std scores NT MFMA: S[b,h,n,m] = qs . kh, K=64 ----------
// tile 128x128, single K stage, 4 waves (2x2), wave 64x64.
__global__ __launch_bounds__(256) void scores_nt(
    const unsigned short* __restrict__ qhb, const unsigned short* __restrict__ khb,
    float* __restrict__ scores) {
  __shared__ unsigned short As[128][72];
  __shared__ unsigned short Bs[128][72];
  const int z = blockIdx.z, b = z >> 3, h = z & 7;
  const unsigned short* Ag = qhb + (size_t)b * NPOS * DMODEL + h * DK;
  const unsigned short* Bg = khb + (size_t)b * NPOS * DMODEL + h * DK;
  const int n0 = blockIdx.x * 128, m0 = blockIdx.y * 128;
  const int t = threadIdx.x, lane = t & 63, w = t >> 6;
  const int wr = w >> 1, wc = w & 1;
  const int l15 = lane & 15, l4 = lane >> 4;
#pragma unroll
  for (int i = 0; i < 4; ++i) {
    int s = t + i * 256;
    int row = s >> 3, kq = s & 7;
    *(uint4*)&As[row][kq * 8] = *(const uint4*)&Ag[(size_t)(n0 + row) * DMODEL + kq * 8];
    *(uint4*)&Bs[row][kq * 8] = *(const uint4*)&Bg[(size_t)(m0 + row) * DMODEL + kq * 8];
  }
  __syncthreads();
  f32x4 acc[4][4] = {};
  bf16x8 af[4][2], bfr[4][2];
#pragma unroll
  for (int mf = 0; mf < 4; ++mf)
#pragma unroll
    for (int ks = 0; ks < 2; ++ks)
      af[mf][ks] = *(const bf16x8*)&As[wr * 64 + mf * 16 + l15][ks * 32 + l4 * 8];
#pragma unroll
  for (int nf = 0; nf < 4; ++nf)
#pragma unroll
    for (int ks = 0; ks < 2; ++ks)
      bfr[nf][ks] = *(const bf16x8*)&Bs[wc * 64 + nf * 16 + l15][ks * 32 + l4 * 8];
#pragma unroll
  for (int mf = 0; mf < 4; ++mf)
#pragma unroll
    for (int nf = 0; nf < 4; ++nf)
#pragma unroll
      for (int ks = 0; ks < 2; ++ks)
        acc[mf][nf] = __builtin_amdgcn_mfma_f32_16x16x32_bf16(af[mf][ks], bfr[nf][ks],
                                                              acc[mf][nf], 0, 0, 0);
  float* C = scores + (size_t)z * SROW;
#pragma unroll
  for (int mf = 0; mf < 4; ++mf)
#pragma unroll
    for (int nf = 0; nf < 4; ++nf) {
      int rown = n0 + wr * 64 + mf * 16 + l4 * 4;
      int colm = m0 + wc * 64 + nf * 16 + l15;
#pragma unroll
      for (int i = 0; i < 4; ++i)
        C[(size_t)(rown + i) * NPOS + colm] = acc[mf][nf][i];
    }
}

// ---------- K4: pos scores (bf16 q), adds into fp32 scores ----------
__global__ __launch_bounds__(256) void pos_scores_v2b(
    const unsigned short* __restrict__ qhb,  // bf16, pre-scaled by 1/8
    const float* __restrict__ rk,            // (n, m, h, d) fp32
    float* __restrict__ scores) {
  __shared__ float rks[16][8][68];
  const int n = blockIdx.y;
  const int m0 = blockIdx.x * 16;
  const int t = threadIdx.x;
  const int b = t & 7, h = (t >> 3) & 7, mg = t >> 6;
  const unsigned short* qrow = qhb + ((size_t)b * NPOS + n) * DMODEL + h * DK;
  float4 qreg[16];
#pragma unroll
  for (int i = 0; i < 8; ++i) {
    uint4 u = *(const uint4*)&qrow[i * 8];
    qreg[2 * i].x = bflo(u.x); qreg[2 * i].y = bfhi(u.x);
    qreg[2 * i].z = bflo(u.y); qreg[2 * i].w = bfhi(u.y);
    qreg[2 * i + 1].x = bflo(u.z); qreg[2 * i + 1].y = bfhi(u.z);
    qreg[2 * i + 1].z = bflo(u.w); qreg[2 * i + 1].w = bfhi(u.w);
  }
  const float4* src = (const float4*)(rk + ((size_t)n * NPOS + m0) * (NH * DK));
#pragma unroll
  for (int kI = 0; kI < 8; ++kI) {
    const int f = t + kI * 256;
    const float4 val = src[f];
    const int m = f >> 7, hh = (f >> 4) & 7, d4 = f & 15;
    *(float4*)&rks[m][hh][d4 * 4] = val;
  }
  __syncthreads();
  const int mb = mg * 4;
  float4 a0 = make_float4(0.f, 0.f, 0.f, 0.f);
  float4 a1 = a0, a2 = a0, a3 = a0;
#pragma unroll
  for (int d4 = 0; d4 < 16; ++d4) {
    const float4 qv = qreg[d4];
    const float4 r0 = *(const float4*)&rks[mb + 0][h][d4 * 4];
    const float4 r1 = *(const float4*)&rks[mb + 1][h][d4 * 4];
    const float4 r2 = *(const float4*)&rks[mb + 2][h][d4 * 4];
    const float4 r3 = *(const float4*)&rks[mb + 3][h][d4 * 4];
    a0.x += qv.x * r0.x; a0.y += qv.y * r0.y; a0.z += qv.z * r0.z; a0.w += qv.w * r0.w;
    a1.x += qv.x * r1.x; a1.y += qv.y * r1.y; a1.z += qv.z * r1.z; a1.w += qv.w * r1.w;
    a2.x += qv.x * r2.x; a2.y += qv.y * r2.y; a2.z += qv.z * r2.z; a2.w += qv.w * r2.w;
    a3.x += qv.x * r3.x; a3.y += qv.y * r3.y; a3.z += qv.z * r3.z; a3.w += qv.w * r3.w;
  }
  float* srow = scores + ((size_t)(b * NH + h) * NPOS + n) * NPOS + m0 + mb;
  float4 c = *(float4*)srow;
  c.x += a0.x + a0.y + a0.z + a0.w;
  c.y += a1.x + a1.y + a1.z + a1.w;
  c.z += a2.x + a2.y + a2.z + a2.w;
  c.w += a3.x + a3.y + a3.z + a3.w;
  *(float4*)srow = c;
}

// ---------- K5: softmax rows, folds 1/sqrt(dk), writes bf16 P in place ----------
__global__ __launch_bounds__(256) void softmax_bf(float* __restrict__ scores) {
  const int row = blockIdx.x * 4 + (threadIdx.x >> 6);
  const int lane = threadIdx.x & 63;
  float* s = scores + (size_t)row * NPOS;
  unsigned short* p = (unsigned short*)s;  // bf16 P overlays first half of the row
  float v[6];
  float mx = -1e30f;
#pragma unroll
  for (int j = 0; j < 6; ++j) {
    v[j] = s[j * 64 + lane];
    mx = fmaxf(mx, v[j]);
  }
#pragma unroll
  for (int o = 32; o; o >>= 1) mx = fmaxf(mx, __shfl_xor(mx, o, 64));
  float sum = 0.f;
#pragma unroll
  for (int j = 0; j < 6; ++j) {
    v[j] = __expf(v[j] - mx);
    sum += v[j];
  }
#pragma unroll
  for (int o = 32; o; o >>= 1) sum += __shfl_xor(sum, o, 64);
  const float inv = 0.125f / sum;
#pragma unroll
  for (int j = 0; j < 6; ++j) p[j * 64 + lane] = f2bf(v[j] * inv);
}

// ---------- K6: PV NT MFMA: attn[b,n,h,:] = P[bh] @ vhT[bh]^T ----------
// tile 64(M) x 64(N=DK), K=384 in 6 steps; 4 waves 2x2, wave 32x32.
__global__ __launch_bounds__(256) void pv_nt(
    const unsigned short* __restrict__ Pbase,  // bf16, row stride 768 ushorts
    const unsigned short* __restrict__ vhT,    // bf16 [bh][d][n]
    unsigned short* __restrict__ attb) {       // bf16 [3072][512]
  __shared__ unsigned short As[64][72];
  __shared__ unsigned short Bs[64][72];
  const int z = blockIdx.z, b = z >> 3, h = z & 7;
  const int n0 = blockIdx.x * 64;
  const unsigned short* Ag = Pbase + ((size_t)(z * NPOS + n0)) * 768;
  const unsigned short* Bg = vhT + (size_t)z * DK * NPOS;
  const int t = threadIdx.x, lane = t & 63, w = t >> 6;
  const int wr = w >> 1, wc = w & 1;
  const int l15 = lane & 15, l4 = lane >> 4;
  f32x4 acc[2][2] = {};
  for (int kt = 0; kt < 6; ++kt) {
    const int k0 = kt * 64;
#pragma unroll
    for (int i = 0; i < 2; ++i) {
      int s = t + i * 256;
      int row = s >> 3, kq = s & 7;
      *(uint4*)&As[row][kq * 8] = *(const uint4*)&Ag[(size_t)row * 768 + k0 + kq * 8];
      *(uint4*)&Bs[row][kq * 8] = *(const uint4*)&Bg[(size_t)row * NPOS + k0 + kq * 8];
    }
    __syncthreads();
    bf16x8 af[2][2], bfr[2][2];
#pragma unroll
    for (int mf = 0; mf < 2; ++mf)
#pragma unroll
      for (int ks = 0; ks < 2; ++ks)
        af[mf][ks] = *(const bf16x8*)&As[wr * 32 + mf * 16 + l15][ks * 32 + l4 * 8];
#pragma unroll
    for (int nf = 0; nf < 2; ++nf)
#pragma unroll
      for (int ks = 0; ks < 2; ++ks)
        bfr[nf][ks] = *(const bf16x8*)&Bs[wc * 32 + nf * 16 + l15][ks * 32 + l4 * 8];
#pragma unroll
    for (int mf = 0; mf < 2; ++mf)
#pragma unroll
      for (int nf = 0; nf < 2; ++nf)
#pragma unroll
        for (int ks = 0; ks < 2; ++ks)
          acc[mf][nf] = __builtin_amdgcn_mfma_f32_16x16x32_bf16(af[mf][ks], bfr[nf][ks],
                                                                acc[mf][nf], 0, 0, 0);
    __syncthreads();
  }
#pragma unroll
  for (int mf = 0; mf < 2; ++mf)
#pragma unroll
    for (int nf = 0; nf < 2; ++nf) {
      const int n = n0 + wr * 32 + mf * 16 + l4 * 4;
      const int d = wc * 32 + nf * 16 + l15;
#pragma unroll
      for (int i = 0; i < 4; ++i)
        attb[(size_t)(b * NPOS + n + i) * DMODEL + h * DK + d] = f2bf(acc[mf][nf][i]);
    }
}

// ---------- K7: output projection (A bf16) ----------
__global__ __launch_bounds__(256) void proj_o(
    const unsigned short* __restrict__ attb, const unsigned short* __restrict__ WtO,
    const float* __restrict__ bo, float* __restrict__ outp) {
  __shared__ unsigned short As[64][72];
  __shared__ unsigned short Bs[64][72];
  const int m0 = blockIdx.x * 64, n0 = blockIdx.y * 64;
  const int t = threadIdx.x, lane = t & 63, w = t >> 6;
  const int wr = w >> 1, wc = w & 1;
  const int l15 = lane & 15, l4 = lane >> 4;
  f32x4 acc[2][2] = {};
  for (int kt = 0; kt < 8; ++kt) {
    const int k0 = kt * 64;
#pragma unroll
    for (int i = 0; i < 2; ++i) {
      int s = t + i * 256;
      int row = s >> 3, kq = s & 7;
      *(uint4*)&As[row][kq * 8] = *(const uint4*)&attb[(size_t)(m0 + row) * DMODEL + k0 + kq * 8];
      *(uint4*)&Bs[row][kq * 8] = *(const uint4*)&WtO[(size_t)(n0 + row) * DMODEL + k0 + kq * 8];
    }
    __syncthreads();
    bf16x8 af[2][2], bfr[2][2];
#pragma unroll
    for (int mf = 0; mf < 2; ++mf)
#pragma unroll
      for (int ks = 0; ks < 2; ++ks)
        af[mf][ks] = *(const bf16x8*)&As[wr * 32 + mf * 16 + l15][ks * 32 + l4 * 8];
#pragma unroll
    for (int nf = 0; nf < 2; ++nf)
#pragma unroll
      for (int ks = 0; ks < 2; ++ks)
        bfr[nf][ks] = *(const bf16x8*)&Bs[wc * 32 + nf * 16 + l15][ks * 32 + l4 * 8];
#pragma unroll
    for (int mf = 0; mf < 2; ++mf)
#pragma unroll
      for (int nf = 0; nf < 2; ++nf)
#pragma unroll
        for (int ks = 0; ks < 2; ++ks)
          acc[mf][nf] = __builtin_amdgcn_mfma_f32_16x16x32_bf16(af[mf][ks], bfr[nf][ks],
                                                                acc[mf][nf], 0, 0, 0);
    __syncthreads();
  }
#pragma unroll
  for (int mf = 0; mf < 2; ++mf)
#pragma unroll
    for (int nf = 0; nf < 2; ++nf) {
      const int row0 = m0 + wr * 32 + mf * 16 + l4 * 4;
      const int col = n0 + wc * 32 + nf * 16 + l15;
      const float bi = bo[col];
#pragma unroll
      for (int i = 0; i < 4; ++i)
        outp[(size_t)(row0 + i) * DMODEL + col] = acc[mf][nf][i] + bi;
    }
}

extern "C" void kernel_launch(void* const* d_in, const int* in_sizes, int n_in,
                              void* d_out, int out_size, void* d_ws, size_t ws_size,
                              hipStream_t stream) {
  const float* q  = (const float*)d_in[0];
  const float* k  = (const float*)d_in[1];
  const float* v  = (const float*)d_in[2];
  const float* rk = (const float*)d_in[3];
  // d_in[4] = rpos_v: unused by the reference
  const float* Wq = (const float*)d_in[5];
  const float* bq = (const float*)d_in[6];
  const float* Wk = (const float*)d_in[7];
  const float* bk = (const float*)d_in[8];
  const float* Wv = (const float*)d_in[9];
  const float* bv = (const float*)d_in[10];
  const float* Wo = (const float*)d_in[11];
  const float* bo = (const float*)d_in[12];

  const size_t TOK = (size_t)MROWS * DMODEL;  // 1,572,864
  unsigned short* wt   = (unsigned short*)d_ws;       // 4 * 512*512
  unsigned short* qhb  = wt + 4 * DMODEL * DMODEL;
  unsigned short* khb  = qhb + TOK;
  unsigned short* vhT  = khb + TOK;
  unsigned short* attb = vhT + TOK;
  float* scores = (float*)(attb + TOK);               // 64*384*384 fp32
  float* origv = (float*)d_out;
  float* outp = origv + TOK;

  dim3 blk(256);

  convert_w<<<dim3(8, 8, 4), blk, 0, stream>>>(Wq, Wk, Wv, Wo, wt);
  proj_qkv<<<dim3(48, 8, 3), blk, 0, stream>>>(q, k, v, wt, bq, bk, bv,
                                               qhb, khb, origv, vhT);
  scores_nt<<<dim3(3, 3, 64), blk, 0, stream>>>(qhb, khb, scores);
  pos_scores_v2b<<<dim3(24, 384), blk, 0, stream>>>(qhb, rk, scores);
  softmax_bf<<<dim3((BS * NH * NPOS) / 4), blk, 0, stream>>>(scores);
  pv_nt<<<dim3(6, 1, 64), blk, 0, stream>>>((const unsigned short*)scores, vhT, attb);
  proj_o<<<dim3(48, 8), blk, 0, stream>>>(attb, wt + 3 * DMODEL * DMODEL, bo, outp);
}

// Round 4
// 154.859 us; speedup vs baseline: 2.7124x; 1.1355x over previous
//
#include <hip/hip_runtime.h>

#define NPOS 384
#define DMODEL 512
#define NH 8
#define DK 64
#define BS 8
#define MROWS (BS * NPOS)     // 3072
#define SROW (NPOS * NPOS)    // 147456

typedef __attribute__((ext_vector_type(8))) short bf16x8;
typedef __attribute__((ext_vector_type(4))) float f32x4;

__device__ __forceinline__ unsigned short f2bf(float x) {
  unsigned int u = __float_as_uint(x);
  return (unsigned short)((u + 0x7fffu + ((u >> 16) & 1u)) >> 16);
}
__device__ __forceinline__ unsigned int pk2(float lo, float hi) {
  unsigned int ul = __float_as_uint(lo), uh = __float_as_uint(hi);
  ul = (ul + 0x7fffu + ((ul >> 16) & 1u)) >> 16;
  uh = (uh + 0x7fffu + ((uh >> 16) & 1u)) & 0xffff0000u;
  return ul | uh;
}
__device__ __forceinline__ bf16x8 pack8(float4 a, float4 b) {
  union { uint4 u; bf16x8 v; } cv;
  cv.u = make_uint4(pk2(a.x, a.y), pk2(a.z, a.w), pk2(b.x, b.y), pk2(b.z, b.w));
  return cv.v;
}

// ---------- K1: transpose-convert the 4 weight matrices to bf16 [n][k] ----------
__global__ __launch_bounds__(256) void convert_w(
    const float* __restrict__ Wq, const float* __restrict__ Wk,
    const float* __restrict__ Wv, const float* __restrict__ Wo,
    unsigned short* __restrict__ wt) {
  __shared__ float s[64][68];
  const int z = blockIdx.z;
  const float* W = z == 0 ? Wq : z == 1 ? Wk : z == 2 ? Wv : Wo;
  unsigned short* out = wt + (size_t)z * DMODEL * DMODEL;
  const int k0 = blockIdx.x * 64, n0 = blockIdx.y * 64;
  const int t = threadIdx.x;
#pragma unroll
  for (int i = 0; i < 4; ++i) {
    int f = t + i * 256;
    int kr = f >> 4, q4 = f & 15;
    *(float4*)&s[kr][q4 * 4] = *(const float4*)&W[(size_t)(k0 + kr) * DMODEL + n0 + q4 * 4];
  }
  __syncthreads();
#pragma unroll
  for (int i = 0; i < 2; ++i) {
    int slot = t + i * 256;
    int n = slot >> 3, kq = slot & 7;
    unsigned int p[4];
#pragma unroll
    for (int j = 0; j < 4; ++j)
      p[j] = pk2(s[kq * 8 + j * 2][n], s[kq * 8 + j * 2 + 1][n]);
    *(uint4*)&out[(size_t)(n0 + n) * DMODEL + k0 + kq * 8] = make_uint4(p[0], p[1], p[2], p[3]);
  }
}

// ---------- K1b: convert q,k,v inputs to bf16 (same layout) ----------
__global__ __launch_bounds__(256) void convert_in(
    const float* __restrict__ qin, const float* __restrict__ kin,
    const float* __restrict__ vin, unsigned short* __restrict__ qkvb) {
  const int z = blockIdx.y;
  const float* src = z == 0 ? qin : z == 1 ? kin : vin;
  unsigned short* dst = qkvb + (size_t)z * MROWS * DMODEL;
  const size_t i = ((size_t)blockIdx.x * 256 + threadIdx.x) * 8;
  float4 a = *(const float4*)&src[i];
  float4 b = *(const float4*)&src[i + 4];
  union { uint4 u; bf16x8 v; } cv;
  cv.u = make_uint4(pk2(a.x, a.y), pk2(a.z, a.w), pk2(b.x, b.y), pk2(b.z, b.w));
  *(uint4*)&dst[i] = cv.u;
}

// ---------- K2: fused Q/K/V projections via MFMA (z selects), A in bf16 ----------
// tile 64x64, BK=64, 4 waves (2x2), wave computes 32x32.
__global__ __launch_bounds__(256) void proj_qkv(
    const unsigned short* __restrict__ qkvb,
    const unsigned short* __restrict__ wt,
    const float* __restrict__ bq, const float* __restrict__ bk, const float* __restrict__ bv,
    unsigned short* __restrict__ qhb, unsigned short* __restrict__ khb,
    float* __restrict__ origv, unsigned short* __restrict__ vhT) {
  __shared__ unsigned short As[64][72];
  __shared__ unsigned short Bs[64][72];
  const int z = blockIdx.z;
  const unsigned short* A = qkvb + (size_t)z * MROWS * DMODEL;
  const unsigned short* Wt = wt + (size_t)z * DMODEL * DMODEL;
  const float* bias = z == 0 ? bq : z == 1 ? bk : bv;
  const int m0 = blockIdx.x * 64, n0 = blockIdx.y * 64;
  const int t = threadIdx.x, lane = t & 63, w = t >> 6;
  const int wr = w >> 1, wc = w & 1;
  const int l15 = lane & 15, l4 = lane >> 4;
  f32x4 acc[2][2] = {};
  for (int kt = 0; kt < 8; ++kt) {
    const int k0 = kt * 64;
#pragma unroll
    for (int i = 0; i < 2; ++i) {
      int s = t + i * 256;
      int row = s >> 3, kq = s & 7;
      *(uint4*)&As[row][kq * 8] = *(const uint4*)&A[(size_t)(m0 + row) * DMODEL + k0 + kq * 8];
      *(uint4*)&Bs[row][kq * 8] = *(const uint4*)&Wt[(size_t)(n0 + row) * DMODEL + k0 + kq * 8];
    }
    __syncthreads();
    bf16x8 af[2][2], bfr[2][2];
#pragma unroll
    for (int mf = 0; mf < 2; ++mf)
#pragma unroll
      for (int ks = 0; ks < 2; ++ks)
        af[mf][ks] = *(const bf16x8*)&As[wr * 32 + mf * 16 + l15][ks * 32 + l4 * 8];
#pragma unroll
    for (int nf = 0; nf < 2; ++nf)
#pragma unroll
      for (int ks = 0; ks < 2; ++ks)
        bfr[nf][ks] = *(const bf16x8*)&Bs[wc * 32 + nf * 16 + l15][ks * 32 + l4 * 8];
#pragma unroll
    for (int mf = 0; mf < 2; ++mf)
#pragma unroll
      for (int nf = 0; nf < 2; ++nf)
#pragma unroll
        for (int ks = 0; ks < 2; ++ks)
          acc[mf][nf] = __builtin_amdgcn_mfma_f32_16x16x32_bf16(af[mf][ks], bfr[nf][ks],
                                                                acc[mf][nf], 0, 0, 0);
    __syncthreads();
  }
#pragma unroll
  for (int mf = 0; mf < 2; ++mf)
#pragma unroll
    for (int nf = 0; nf < 2; ++nf) {
      const int row0 = m0 + wr * 32 + mf * 16 + l4 * 4;
      const int col = n0 + wc * 32 + nf * 16 + l15;
      const float bi = bias[col];
      if (z == 0) {
#pragma unroll
        for (int i = 0; i < 4; ++i)
          qhb[(size_t)(row0 + i) * DMODEL + col] = f2bf((acc[mf][nf][i] + bi) * 0.125f);
      } else if (z == 1) {
#pragma unroll
        for (int i = 0; i < 4; ++i)
          khb[(size_t)(row0 + i) * DMODEL + col] = f2bf(acc[mf][nf][i] + bi);
      } else {
        const int b = row0 / NPOS, n = row0 - b * NPOS;
        const int h = col >> 6, d = col & 63;
        float vals[4];
#pragma unroll
        for (int i = 0; i < 4; ++i) {
          vals[i] = acc[mf][nf][i] + bi;
          origv[(size_t)(row0 + i) * DMODEL + col] = vals[i];
        }
        ushort4 pk;
        pk.x = f2bf(vals[0]); pk.y = f2bf(vals[1]);
        pk.z = f2bf(vals[2]); pk.w = f2bf(vals[3]);
        *(ushort4*)&vhT[((size_t)((b * NH + h) * DK + d)) * NPOS + n] = pk;
      }
    }
}

// ---------- K3: std scores NT MFMA: S[b,h,n,m] = qs . kh, K=64 ----------
// tile 128x128, single K stage, 4 waves (2x2), wave 64x64.
__global__ __launch_bounds__(256) void scores_nt(
    const unsigned short* __restrict__ qhb, const unsigned short* __restrict__ khb,
    float* __restrict__ scores) {
  __shared__ unsigned short As[128][72];
  __shared__ unsigned short Bs[128][72];
  const int z = blockIdx.z, b = z >> 3, h = z & 7;
  const unsigned short* Ag = qhb + (size_t)b * NPOS * DMODEL + h * DK;
  const unsigned short* Bg = khb + (size_t)b * NPOS * DMODEL + h * DK;
  const int n0 = blockIdx.x * 128, m0 = blockIdx.y * 128;
  const int t = threadIdx.x, lane = t & 63, w = t >> 6;
  const int wr = w >> 1, wc = w & 1;
  const int l15 = lane & 15, l4 = lane >> 4;
#pragma unroll
  for (int i = 0; i < 4; ++i) {
    int s = t + i * 256;
    int row = s >> 3, kq = s & 7;
    *(uint4*)&As[row][kq * 8] = *(const uint4*)&Ag[(size_t)(n0 + row) * DMODEL + kq * 8];
    *(uint4*)&Bs[row][kq * 8] = *(const uint4*)&Bg[(size_t)(m0 + row) * DMODEL + kq * 8];
  }
  __syncthreads();
  f32x4 acc[4][4] = {};
  bf16x8 af[4][2], bfr[4][2];
#pragma unroll
  for (int mf = 0; mf < 4; ++mf)
#pragma unroll
    for (int ks = 0; ks < 2; ++ks)
      af[mf][ks] = *(const bf16x8*)&As[wr * 64 + mf * 16 + l15][ks * 32 + l4 * 8];
#pragma unroll
  for (int nf = 0; nf < 4; ++nf)
#pragma unroll
    for (int ks = 0; ks < 2; ++ks)
      bfr[nf][ks] = *(const bf16x8*)&Bs[wc * 64 + nf * 16 + l15][ks * 32 + l4 * 8];
#pragma unroll
  for (int mf = 0; mf < 4; ++mf)
#pragma unroll
    for (int nf = 0; nf < 4; ++nf)
#pragma unroll
      for (int ks = 0; ks < 2; ++ks)
        acc[mf][nf] = __builtin_amdgcn_mfma_f32_16x16x32_bf16(af[mf][ks], bfr[nf][ks],
                                                              acc[mf][nf], 0, 0, 0);
  float* C = scores + (size_t)z * SROW;
#pragma unroll
  for (int mf = 0; mf < 4; ++mf)
#pragma unroll
    for (int nf = 0; nf < 4; ++nf) {
      int rown = n0 + wr * 64 + mf * 16 + l4 * 4;
      int colm = m0 + wc * 64 + nf * 16 + l15;
#pragma unroll
      for (int i = 0; i < 4; ++i)
        C[(size_t)(rown + i) * NPOS + colm] = acc[mf][nf][i];
    }
}

// ---------- K4: pos scores via MFMA, direct-register, adds into fp32 scores ----
// grid (24 m-tiles, 384 n), block 256 = 4 waves; wave w handles h = {2w, 2w+1}.
// A = rk rows (m), B = q cols (b; cols 8-15 duped/discarded). No LDS, no barrier.
__global__ __launch_bounds__(256) void pos_scores_mfma(
    const unsigned short* __restrict__ qhb,  // bf16 (b,n,h*64+d), prescaled 1/8
    const float* __restrict__ rk,            // (n,m,h,d) f32
    float* __restrict__ scores) {            // (b,h,n,m) f32, RMW add
  const int n = blockIdx.y;
  const int m0 = blockIdx.x * 16;
  const int t = threadIdx.x, lane = t & 63, w = t >> 6;
  const int l15 = lane & 15, l4 = lane >> 4;
  const int bcol = l15 & 7;
  const float* rkrow = rk + ((size_t)n * NPOS + m0 + l15) * (NH * DK);
  const unsigned short* qp = qhb + ((size_t)bcol * NPOS + n) * DMODEL;
#pragma unroll
  for (int hp = 0; hp < 2; ++hp) {
    const int h = w * 2 + hp;
    const int base = h * DK;
    f32x4 acc = {};
#pragma unroll
    for (int ks = 0; ks < 2; ++ks) {
      const int off = base + ks * 32 + l4 * 8;
      const float4 ra = *(const float4*)&rkrow[off];
      const float4 rb = *(const float4*)&rkrow[off + 4];
      bf16x8 af = pack8(ra, rb);
      bf16x8 bfr = *(const bf16x8*)&qp[off];
      acc = __builtin_amdgcn_mfma_f32_16x16x32_bf16(af, bfr, acc, 0, 0, 0);
    }
    if (l15 < 8) {
      float* srow = scores + ((size_t)(l15 * NH + h) * NPOS + n) * NPOS + m0 + l4 * 4;
      float4 c = *(float4*)srow;
      c.x += acc[0]; c.y += acc[1]; c.z += acc[2]; c.w += acc[3];
      *(float4*)srow = c;
    }
  }
}

// ---------- K5: softmax rows, folds 1/sqrt(dk), writes bf16 P in place ----------
__global__ __launch_bounds__(256) void softmax_bf(float* __restrict__ scores) {
  const int row = blockIdx.x * 4 + (threadIdx.x >> 6);
  const int lane = threadIdx.x & 63;
  float* s = scores + (size_t)row * NPOS;
  unsigned short* p = (unsigned short*)s;  // bf16 P overlays first half of the row
  float v[6];
  float mx = -1e30f;
#pragma unroll
  for (int j = 0; j < 6; ++j) {
    v[j] = s[j * 64 + lane];
    mx = fmaxf(mx, v[j]);
  }
#pragma unroll
  for (int o = 32; o; o >>= 1) mx = fmaxf(mx, __shfl_xor(mx, o, 64));
  float sum = 0.f;
#pragma unroll
  for (int j = 0; j < 6; ++j) {
    v[j] = __expf(v[j] - mx);
    sum += v[j];
  }
#pragma unroll
  for (int o = 32; o; o >>= 1) sum += __shfl_xor(sum, o, 64);
  const float inv = 0.125f / sum;
#pragma unroll
  for (int j = 0; j < 6; ++j) p[j * 64 + lane] = f2bf(v[j] * inv);
}

// ---------- K6: PV NT MFMA: attn[b,n,h,:] = P[bh] @ vhT[bh]^T ----------
__global__ __launch_bounds__(256) void pv_nt(
    const unsigned short* __restrict__ Pbase,  // bf16, row stride 768 ushorts
    const unsigned short* __restrict__ vhT,    // bf16 [bh][d][n]
    unsigned short* __restrict__ attb) {       // bf16 [3072][512]
  __shared__ unsigned short As[64][72];
  __shared__ unsigned short Bs[64][72];
  const int z = blockIdx.z, b = z >> 3, h = z & 7;
  const int n0 = blockIdx.x * 64;
  const unsigned short* Ag = Pbase + ((size_t)(z * NPOS + n0)) * 768;
  const unsigned short* Bg = vhT + (size_t)z * DK * NPOS;
  const int t = threadIdx.x, lane = t & 63, w = t >> 6;
  const int wr = w >> 1, wc = w & 1;
  const int l15 = lane & 15, l4 = lane >> 4;
  f32x4 acc[2][2] = {};
  for (int kt = 0; kt < 6; ++kt) {
    const int k0 = kt * 64;
#pragma unroll
    for (int i = 0; i < 2; ++i) {
      int s = t + i * 256;
      int row = s >> 3, kq = s & 7;
      *(uint4*)&As[row][kq * 8] = *(const uint4*)&Ag[(size_t)row * 768 + k0 + kq * 8];
      *(uint4*)&Bs[row][kq * 8] = *(const uint4*)&Bg[(size_t)row * NPOS + k0 + kq * 8];
    }
    __syncthreads();
    bf16x8 af[2][2], bfr[2][2];
#pragma unroll
    for (int mf = 0; mf < 2; ++mf)
#pragma unroll
      for (int ks = 0; ks < 2; ++ks)
        af[mf][ks] = *(const bf16x8*)&As[wr * 32 + mf * 16 + l15][ks * 32 + l4 * 8];
#pragma unroll
    for (int nf = 0; nf < 2; ++nf)
#pragma unroll
      for (int ks = 0; ks < 2; ++ks)
        bfr[nf][ks] = *(const bf16x8*)&Bs[wc * 32 + nf * 16 + l15][ks * 32 + l4 * 8];
#pragma unroll
    for (int mf = 0; mf < 2; ++mf)
#pragma unroll
      for (int nf = 0; nf < 2; ++nf)
#pragma unroll
        for (int ks = 0; ks < 2; ++ks)
          acc[mf][nf] = __builtin_amdgcn_mfma_f32_16x16x32_bf16(af[mf][ks], bfr[nf][ks],
                                                                acc[mf][nf], 0, 0, 0);
    __syncthreads();
  }
#pragma unroll
  for (int mf = 0; mf < 2; ++mf)
#pragma unroll
    for (int nf = 0; nf < 2; ++nf) {
      const int n = n0 + wr * 32 + mf * 16 + l4 * 4;
      const int d = wc * 32 + nf * 16 + l15;
#pragma unroll
      for (int i = 0; i < 4; ++i)
        attb[(size_t)(b * NPOS + n + i) * DMODEL + h * DK + d] = f2bf(acc[mf][nf][i]);
    }
}

// ---------- K7: output projection (A bf16) ----------
__global__ __launch_bounds__(256) void proj_o(
    const unsigned short* __restrict__ attb, const unsigned short* __restrict__ WtO,
    const float* __restrict__ bo, float* __restrict__ outp) {
  __shared__ unsigned short As[64][72];
  __shared__ unsigned short Bs[64][72];
  const int m0 = blockIdx.x * 64, n0 = blockIdx.y * 64;
  const int t = threadIdx.x, lane = t & 63, w = t >> 6;
  const int wr = w >> 1, wc = w & 1;
  const int l15 = lane & 15, l4 = lane >> 4;
  f32x4 acc[2][2] = {};
  for (int kt = 0; kt < 8; ++kt) {
    const int k0 = kt * 64;
#pragma unroll
    for (int i = 0; i < 2; ++i) {
      int s = t + i * 256;
      int row = s >> 3, kq = s & 7;
      *(uint4*)&As[row][kq * 8] = *(const uint4*)&attb[(size_t)(m0 + row) * DMODEL + k0 + kq * 8];
      *(uint4*)&Bs[row][kq * 8] = *(const uint4*)&WtO[(size_t)(n0 + row) * DMODEL + k0 + kq * 8];
    }
    __syncthreads();
    bf16x8 af[2][2], bfr[2][2];
#pragma unroll
    for (int mf = 0; mf < 2; ++mf)
#pragma unroll
      for (int ks = 0; ks < 2; ++ks)
        af[mf][ks] = *(const bf16x8*)&As[wr * 32 + mf * 16 + l15][ks * 32 + l4 * 8];
#pragma unroll
    for (int nf = 0; nf < 2; ++nf)
#pragma unroll
      for (int ks = 0; ks < 2; ++ks)
        bfr[nf][ks] = *(const bf16x8*)&Bs[wc * 32 + nf * 16 + l15][ks * 32 + l4 * 8];
#pragma unroll
    for (int mf = 0; mf < 2; ++mf)
#pragma unroll
      for (int nf = 0; nf < 2; ++nf)
#pragma unroll
        for (int ks = 0; ks < 2; ++ks)
          acc[mf][nf] = __builtin_amdgcn_mfma_f32_16x16x32_bf16(af[mf][ks], bfr[nf][ks],
                                                                acc[mf][nf], 0, 0, 0);
    __syncthreads();
  }
#pragma unroll
  for (int mf = 0; mf < 2; ++mf)
#pragma unroll
    for (int nf = 0; nf < 2; ++nf) {
      const int row0 = m0 + wr * 32 + mf * 16 + l4 * 4;
      const int col = n0 + wc * 32 + nf * 16 + l15;
      const float bi = bo[col];
#pragma unroll
      for (int i = 0; i < 4; ++i)
        outp[(size_t)(row0 + i) * DMODEL + col] = acc[mf][nf][i] + bi;
    }
}

extern "C" void kernel_launch(void* const* d_in, const int* in_sizes, int n_in,
                              void* d_out, int out_size, void* d_ws, size_t ws_size,
                              hipStream_t stream) {
  const float* q  = (const float*)d_in[0];
  const float* k  = (const float*)d_in[1];
  const float* v  = (const float*)d_in[2];
  const float* rk = (const float*)d_in[3];
  // d_in[4] = rpos_v: unused by the reference
  const float* Wq = (const float*)d_in[5];
  const float* bq = (const float*)d_in[6];
  const float* Wk = (const float*)d_in[7];
  const float* bk = (const float*)d_in[8];
  const float* Wv = (const float*)d_in[9];
  const float* bv = (const float*)d_in[10];
  const float* Wo = (const float*)d_in[11];
  const float* bo = (const float*)d_in[12];

  const size_t TOK = (size_t)MROWS * DMODEL;  // 1,572,864
  unsigned short* wt   = (unsigned short*)d_ws;       // 4 * 512*512
  unsigned short* qhb  = wt + 4 * DMODEL * DMODEL;
  unsigned short* khb  = qhb + TOK;
  unsigned short* vhT  = khb + TOK;
  unsigned short* attb = vhT + TOK;
  float* scores = (float*)(attb + TOK);               // 64*384*384 fp32
  // bf16 copies of q,k,v inputs alias the scores region (consumed before
  // scores_nt overwrites it): 3*TOK ushorts = 9.4 MB < 37.7 MB.
  unsigned short* qkvb = (unsigned short*)scores;
  float* origv = (float*)d_out;
  float* outp = origv + TOK;

  dim3 blk(256);

  convert_w<<<dim3(8, 8, 4), blk, 0, stream>>>(Wq, Wk, Wv, Wo, wt);
  convert_in<<<dim3(768, 3), blk, 0, stream>>>(q, k, v, qkvb);
  proj_qkv<<<dim3(48, 8, 3), blk, 0, stream>>>(qkvb, wt, bq, bk, bv,
                                               qhb, khb, origv, vhT);
  scores_nt<<<dim3(3, 3, 64), blk, 0, stream>>>(qhb, khb, scores);
  pos_scores_mfma<<<dim3(24, 384), blk, 0, stream>>>(qhb, rk, scores);
  softmax_bf<<<dim3((BS * NH * NPOS) / 4), blk, 0, stream>>>(scores);
  pv_nt<<<dim3(6, 1, 64), blk, 0, stream>>>((const unsigned short*)scores, vhT, attb);
  proj_o<<<dim3(48, 8), blk, 0, stream>>>(attb, wt + 3 * DMODEL * DMODEL, bo, outp);
}